// Round 10
// baseline (440.504 us; speedup 1.0000x reference)
//
#include <hip/hip_runtime.h>

#define NT     65536
#define NGRID  28
#define NX     19
#define HDIM   20
#define PF     4
#define CHUNK  256
#define WARM   64
#define NCHUNK (NT / CHUNK)   // 256

typedef float f2 __attribute__((ext_vector_type(2)));
typedef float f4 __attribute__((ext_vector_type(4)));

#if __has_builtin(__builtin_amdgcn_exp2f)
#define EXP2(x) __builtin_amdgcn_exp2f(x)
#else
#define EXP2(x) exp2f(x)
#endif
#define L2E 1.4426950408889634f

__device__ __forceinline__ float frcp(float v) { return __builtin_amdgcn_rcpf(v); }

// packed f32 fma via compiler (v_pk_fma_f32) — NO inline asm: asm "v"
// constraints forced AGPR-parked weights into arch VGPRs with
// v_accvgpr_read copies every use (~128 cy/step measured r5-r9).
__device__ __forceinline__ f2 fm2(f2 a, f2 b, f2 c) {
    return __builtin_elementwise_fma(a, b, c);
}

// 4-lane (quad) sum via DPP quad_perm butterflies — all lanes get the sum.
__device__ __forceinline__ float qsum(float v) {
    float a = v + __builtin_bit_cast(float,
        __builtin_amdgcn_update_dpp(0, __builtin_bit_cast(int, v), 0xB1, 0xF, 0xF, true));
    return a + __builtin_bit_cast(float,
        __builtin_amdgcn_update_dpp(0, __builtin_bit_cast(int, a), 0x4E, 0xF, 0xF, true));
}

// Combined 48-wide weight vector of gate row r, output-feedback absorbed:
// [0..18]=W_ih[r][0..18], [19]=0 (x pad), [20..39]=W_hh[r]+W_ih[r][19]*W_out, [40..47]=0
__device__ __forceinline__ float gw(const float* W_ih, const float* W_hh,
                                    const float* W_out, int r, int k) {
    if (k < NX) return W_ih[r * 20 + k];
    if (k >= 20 && k < 40)
        return fmaf(W_ih[r * 20 + 19], W_out[k - 20], W_hh[r * 20 + (k - 20)]);
    return 0.f;
}

// One wave per (chunk, cell). ALL 80 gate rows are quad-distributed: quad qd
// owns rows 5qd..5qd+4; each lane computes 12-wide quarter-dots of all 5 rows
// from 3 shared b128 operand reads (Q0-Q2) + DPP quad-reduce. Lane qi
// activates row 5qd+qi; lane qi==3 also row 5qd+4. The out row (w_out) is a
// 6th shared computation (identical on every quad); lane 0 stores out_{t-1}.
// LDS reads/step: 4 b128 (was 14 — LDS return bandwidth was the r9 binding
// constraint at ~448 cy/SIMD-step). Output feedback absorbed into W_hh'.
__global__ __launch_bounds__(64, 2) void lstm_qrow_kernel(
    const float* __restrict__ x,      // (NT, NGRID, NX)
    const float* __restrict__ W_ih,   // (80, 20)
    const float* __restrict__ W_hh,   // (80, 20)
    const float* __restrict__ b_ih,   // (80,)
    const float* __restrict__ b_hh,   // (80,)
    const float* __restrict__ W_out,  // (1, 20)
    const float* __restrict__ b_out,  // (1,)
    float* __restrict__ out)          // (NT, NGRID)
{
    __shared__ __align__(16) float cls[2][48];   // [x_t(20) | h_{t-1}(20) | 0(8)], ping-pong
    __shared__ __align__(16) float gls[20][4];   // activated gates, unit-major (si,sf,tg,so)

    const int b  = blockIdx.x;
    const int ci = b / NGRID;
    const int g  = b - ci * NGRID;
    const int l  = threadIdx.x;
    const int qd = l >> 2;          // quad index 0..15
    const int qi = l & 3;           // lane-in-quad
    const int qb = 12 * qi;         // quarter base in combined vector

    const int tstart = ci * CHUNK;
    const int t0     = (ci == 0) ? 0 : tstart - WARM;

    const float bout = b_out[0];

    // ---- quarter weights for this quad's 5 rows (static arrays) ----
    f2 w0[6], w1[6], w2[6], w3[6], w4[6], wo[6];
#pragma unroll
    for (int m = 0; m < 6; ++m) {
        const int k0 = qb + 2 * m, k1 = k0 + 1;
        w0[m] = f2{gw(W_ih, W_hh, W_out, 5 * qd + 0, k0), gw(W_ih, W_hh, W_out, 5 * qd + 0, k1)};
        w1[m] = f2{gw(W_ih, W_hh, W_out, 5 * qd + 1, k0), gw(W_ih, W_hh, W_out, 5 * qd + 1, k1)};
        w2[m] = f2{gw(W_ih, W_hh, W_out, 5 * qd + 2, k0), gw(W_ih, W_hh, W_out, 5 * qd + 2, k1)};
        w3[m] = f2{gw(W_ih, W_hh, W_out, 5 * qd + 3, k0), gw(W_ih, W_hh, W_out, 5 * qd + 3, k1)};
        w4[m] = f2{gw(W_ih, W_hh, W_out, 5 * qd + 4, k0), gw(W_ih, W_hh, W_out, 5 * qd + 4, k1)};
        wo[m] = f2{(k0 >= 20 && k0 < 40) ? W_out[k0 - 20] : 0.f,
                   (k1 >= 20 && k1 < 40) ? W_out[k1 - 20] : 0.f};
    }

    // ---- per-lane activation rows ----
    const int rp = 5 * qd + qi;             // primary row (activated by this lane)
    const int rs = 5 * qd + 4;              // secondary row (activated by qi==3)
    const int qp = rp / 20, qs = rs / 20;   // gate class 0=i,1=f,2=g,3=o
    float* gpp = &gls[rp % 20][qp];
    float* gps = &gls[rs % 20][qs];
    // act = A + B * rcp(1 + exp2(m*a)): sigmoid m=-L2E,A=0,B=1; tanh m=2L2E,A=1,B=-2
    const float m1p = (qp == 2) ? (2.f * L2E) : -L2E;
    const float A1p = (qp == 2) ?  1.f :  0.f;
    const float B1p = (qp == 2) ? -2.f :  1.f;
    const float m1s = (qs == 2) ? (2.f * L2E) : -L2E;
    const float A1s = (qs == 2) ?  1.f :  0.f;
    const float B1s = (qs == 2) ? -2.f :  1.f;

    // biases (absorbed: + W_ih[r][19]*b_out for t>0; unabsorbed at true t=0)
    const float bp0 = b_ih[rp] + b_hh[rp];
    const float bpf = fmaf(W_ih[rp * 20 + 19], bout, bp0);
    const float bs0 = b_ih[rs] + b_hh[rs];
    const float bsf = fmaf(W_ih[rs * 20 + 19], bout, bs0);
    float bp = (ci == 0) ? bp0 : bpf;
    float bs = (ci == 0) ? bs0 : bsf;

    // ---- x pipeline: lane k<19 holds x[t][g][k]; depth-PF register prefetch ----
    const int    kl   = (l < NX) ? l : 0;
    const float* xptr = x + (size_t)g * NX + kl;
    const size_t tsx  = (size_t)NGRID * NX;
    float xr[PF];
#pragma unroll
    for (int p = 0; p < PF; ++p) {
        int tp = t0 + 1 + p; if (tp > NT - 1) tp = NT - 1;
        xr[p] = xptr[(size_t)tp * tsx];
    }
    // prime LDS: pads, h_{t0-1}=0, x_{t0}
    if (l < 8)    { cls[0][40 + l] = 0.f; cls[1][40 + l] = 0.f; }
    if (l < HDIM) { cls[0][20 + l] = 0.f; cls[0][l] = xptr[(size_t)t0 * tsx]; }

    float  c  = 0.f;
    int    px = 0;
    float* op = out + (size_t)tstart * NGRID + g;

#define ROW6(WARR, DST)                                                        \
    { f2 a_ = fm2(P0, WARR[0], f2{0.f, 0.f});                                  \
      a_ = fm2(P1, WARR[1], a_); a_ = fm2(P2, WARR[2], a_);                    \
      a_ = fm2(P3, WARR[3], a_); a_ = fm2(P4, WARR[4], a_);                    \
      a_ = fm2(P5, WARR[5], a_);                                               \
      DST = qsum(a_.x + a_.y); }

#define STEP(T, DO_STORE)                                                      \
    {                                                                          \
        if (l < HDIM) cls[px ^ 1][l] = xr[0];        /* stage x_{T+1} */       \
        int tf_ = (T) + 1 + PF; if (tf_ > NT - 1) tf_ = NT - 1;                \
        const float xf_ = xptr[(size_t)tf_ * tsx];                             \
        /* shared quarter operands: 3 b128, 4 distinct addrs/wave */           \
        const f4 Q0 = *(const f4*)&cls[px][qb];                                \
        const f4 Q1 = *(const f4*)&cls[px][qb + 4];                            \
        const f4 Q2 = *(const f4*)&cls[px][qb + 8];                            \
        const f2 P0 = f2{Q0.x, Q0.y}, P1 = f2{Q0.z, Q0.w};                     \
        const f2 P2 = f2{Q1.x, Q1.y}, P3 = f2{Q1.z, Q1.w};                     \
        const f2 P4 = f2{Q2.x, Q2.y}, P5 = f2{Q2.z, Q2.w};                     \
        float s0_, s1_, s2_, s3_, s4_, vo_;                                    \
        ROW6(w0, s0_) ROW6(w1, s1_) ROW6(w2, s2_)                              \
        ROW6(w3, s3_) ROW6(w4, s4_) ROW6(wo, vo_)                              \
        /* primary activation (cndmask select — no dynamic indexing) */        \
        const float sp_ = (qi == 0) ? s0_ : (qi == 1) ? s1_                    \
                        : (qi == 2) ? s2_ : s3_;                               \
        const float ap_ = sp_ + bp;                                            \
        const float ep_ = EXP2(m1p * ap_);                                     \
        *gpp = fmaf(B1p, frcp(1.f + ep_), A1p);                                \
        if (qi == 3) {                               /* secondary row */       \
            const float as_ = s4_ + bs;                                        \
            const float es_ = EXP2(m1s * as_);                                 \
            *gps = fmaf(B1s, frcp(1.f + es_), A1s);                            \
        }                                                                      \
        if (DO_STORE) { if (l == 0) *op = vo_ + bout; op += NGRID; }           \
        asm volatile("s_waitcnt lgkmcnt(0)" ::: "memory");                     \
        if (l < HDIM) {                              /* state update */        \
            const f4 gv = *(const f4*)&gls[l][0];    /* si, sf, tg, so */      \
            c = fmaf(gv.y, c, gv.x * gv.z);                                    \
            const float ec = EXP2(2.f * L2E * c);                              \
            cls[px ^ 1][20 + l] = gv.w * (1.f - 2.f * frcp(1.f + ec));         \
        }                                                                      \
        _Pragma("unroll")                                                      \
        for (int i_ = 0; i_ < PF - 1; ++i_) xr[i_] = xr[i_ + 1];               \
        xr[PF - 1] = xf_;                                                      \
        px ^= 1;                                                               \
    }

    // peeled first step (unabsorbed bias for chunk 0), then warm, then main.
    // unroll 2: px parity is compile-time (warm=64, main=256, both even).
    STEP(t0, false);
    bp = bpf; bs = bsf;
#pragma unroll 2
    for (int t = t0 + 1; t <= tstart; ++t) STEP(t, false);
#pragma unroll 2
    for (int t = tstart + 1; t <= tstart + CHUNK; ++t) STEP(t, true);
#undef STEP
#undef ROW6
}

extern "C" void kernel_launch(void* const* d_in, const int* in_sizes, int n_in,
                              void* d_out, int out_size, void* d_ws, size_t ws_size,
                              hipStream_t stream) {
    const float* x     = (const float*)d_in[0];
    const float* W_ih  = (const float*)d_in[1];
    const float* W_hh  = (const float*)d_in[2];
    const float* b_ih  = (const float*)d_in[3];
    const float* b_hh  = (const float*)d_in[4];
    const float* W_out = (const float*)d_in[5];
    const float* b_out = (const float*)d_in[6];
    float* out = (float*)d_out;

    lstm_qrow_kernel<<<dim3(NCHUNK * NGRID), dim3(64), 0, stream>>>(
        x, W_ih, W_hh, b_ih, b_hh, W_out, b_out, out);
}

// Round 11
// 403.989 us; speedup vs baseline: 1.0904x; 1.0904x over previous
//
#include <hip/hip_runtime.h>

#define NT     65536
#define NGRID  28
#define NX     19
#define HDIM   20
#define PF     4
#define CHUNK  256
#define WARM   64
#define NCHUNK (NT / CHUNK)   // 256
#define WPB    4              // waves per block (independent work units)

typedef float f2 __attribute__((ext_vector_type(2)));
typedef float f4 __attribute__((ext_vector_type(4)));

#if __has_builtin(__builtin_amdgcn_exp2f)
#define EXP2(x) __builtin_amdgcn_exp2f(x)
#else
#define EXP2(x) exp2f(x)
#endif
#define L2E 1.4426950408889634f

__device__ __forceinline__ float frcp(float v) { return __builtin_amdgcn_rcpf(v); }

// packed f32 FMA: acc.lo += a.lo*b.lo, acc.hi += a.hi*b.hi
__device__ __forceinline__ void pk_fma(f2& acc, f2 a, f2 b) {
    asm("v_pk_fma_f32 %0, %1, %2, %0" : "+v"(acc) : "v"(a), "v"(b));
}

// 4-lane (quad) sum via DPP quad_perm butterflies — all lanes get the sum.
__device__ __forceinline__ float quad_sum(float v) {
    float a = v + __builtin_bit_cast(float,
        __builtin_amdgcn_update_dpp(0, __builtin_bit_cast(int, v), 0xB1, 0xF, 0xF, true));
    return a + __builtin_bit_cast(float,
        __builtin_amdgcn_update_dpp(0, __builtin_bit_cast(int, a), 0x4E, 0xF, 0xF, true));
}

// Combined 48-wide weight vector of gate row r, output-feedback absorbed:
// [0..18]=W_ih[r][0..18], [19]=0 (x pad), [20..39]=W_hh[r]+W_ih[r][19]*W_out, [40..47]=0
__device__ __forceinline__ float gw(const float* W_ih, const float* W_hh,
                                    const float* W_out, int r, int k) {
    if (k < NX) return W_ih[r * 20 + k];
    if (k >= 20 && k < 40)
        return fmaf(W_ih[r * 20 + 19], W_out[k - 20], W_hh[r * 20 + (k - 20)]);
    return 0.f;
}

// Round-9 structure (lane l owns gate row l; o-rows 64..79 quad-shared over
// 12-wide quarters + DPP reduce; out row computed by every quad from the same
// operand reads; lane 0 stores out_{t-1}; output feedback absorbed into W_hh').
// Round 11: FOUR independent waves per block (one per (chunk,cell) work unit,
// private LDS slices, no barriers). 64-thread blocks were capped by the
// per-CU workgroup-slot limit (~16 blocks/CU -> 4 waves/SIMD, measured occ
// 33-39% across r8/r9); 256-thread blocks give 7 blocks/CU = 28 waves/CU.
__global__ __launch_bounds__(64 * WPB, 2) void lstm_w4_kernel(
    const float* __restrict__ x,      // (NT, NGRID, NX)
    const float* __restrict__ W_ih,   // (80, 20)
    const float* __restrict__ W_hh,   // (80, 20)
    const float* __restrict__ b_ih,   // (80,)
    const float* __restrict__ b_hh,   // (80,)
    const float* __restrict__ W_out,  // (1, 20)
    const float* __restrict__ b_out,  // (1,)
    float* __restrict__ out)          // (NT, NGRID)
{
    __shared__ __align__(16) float cls[WPB][2][48];  // [x_t(20) | h(20) | 0(8)], ping-pong
    __shared__ __align__(16) float gls[WPB][20][4];  // activated gates (si,sf,tg,so)

    const int w  = threadIdx.x >> 6;          // wave in block
    const int u  = blockIdx.x * WPB + w;      // work unit = (chunk, cell)
    const int ci = u / NGRID;
    const int g  = u - ci * NGRID;
    const int l  = threadIdx.x & 63;
    const int qd = l >> 2;          // quad index 0..15
    const int qi = l & 3;           // lane-in-quad
    const int qb = 12 * qi;         // quarter base in combined vector

    float (*cw)[48]  = cls[w];      // this wave's private slices
    float (*gwl)[4]  = gls[w];

    const int tstart = ci * CHUNK;
    const int t0     = (ci == 0) ? 0 : tstart - WARM;

    const int g1 = l / HDIM;        // own row's gate class (0=i,1=f,2=g,3=o)
    const int u1 = l % HDIM;        // own row's unit

    const float bout = b_out[0];

    // ---- own row (row l): 20 f2 over combined k=0..39 ----
    f2 w_own[20];
#pragma unroll
    for (int kk = 0; kk < 20; ++kk)
        w_own[kk] = f2{gw(W_ih, W_hh, W_out, l, 2 * kk),
                       gw(W_ih, W_hh, W_out, l, 2 * kk + 1)};
    const float bb1 = b_ih[l] + b_hh[l];
    const float b1f = fmaf(W_ih[l * 20 + 19], bout, bb1);   // absorbed bias (t>0)
    float b1c = (ci == 0) ? bb1 : b1f;                      // true t=0: prev=0

    // ---- quad-shared o-row rs = 64+qd: this lane's 12-wide quarter ----
    const int rs = 64 + qd;
    f2 w_sh[6];
#pragma unroll
    for (int m = 0; m < 6; ++m)
        w_sh[m] = f2{gw(W_ih, W_hh, W_out, rs, qb + 2 * m),
                     gw(W_ih, W_hh, W_out, rs, qb + 2 * m + 1)};
    const float bbs = b_ih[rs] + b_hh[rs];
    const float bsf = fmaf(W_ih[rs * 20 + 19], bout, bbs);
    float bsc = (ci == 0) ? bbs : bsf;

    // ---- out row quarter: nonzero only in h-part (k 20..39 -> W_out) ----
    f2 w_oq[6];
#pragma unroll
    for (int m = 0; m < 6; ++m) {
        const int k0 = qb + 2 * m, k1 = k0 + 1;
        w_oq[m] = f2{(k0 >= 20 && k0 < 40) ? W_out[k0 - 20] : 0.f,
                     (k1 >= 20 && k1 < 40) ? W_out[k1 - 20] : 0.f};
    }

    // own-row activation (exp2 form): act = A1 + B1 * rcp(1 + exp2(m1*a))
    const float m1 = (g1 == 2) ? (2.f * L2E) : -L2E;
    const float A1 = (g1 == 2) ?  1.f :  0.f;
    const float B1 = (g1 == 2) ? -2.f :  1.f;

    // ---- x pipeline: lane k<19 holds x[t][g][k]; depth-PF register prefetch ----
    const int    kl   = (l < NX) ? l : 0;
    const float* xptr = x + (size_t)g * NX + kl;
    const size_t tsx  = (size_t)NGRID * NX;
    float xr[PF];
#pragma unroll
    for (int p = 0; p < PF; ++p) {
        int tp = t0 + 1 + p; if (tp > NT - 1) tp = NT - 1;
        xr[p] = xptr[(size_t)tp * tsx];
    }
    // prime LDS: pads, h_{t0-1}=0, x_{t0}
    if (l < 8)    { cw[0][40 + l] = 0.f; cw[1][40 + l] = 0.f; }
    if (l < HDIM) { cw[0][20 + l] = 0.f; cw[0][l] = xptr[(size_t)t0 * tsx]; }

    float  c  = 0.f;
    int    px = 0;
    float* op = out + (size_t)tstart * NGRID + g;

#define STEP(T, DO_STORE)                                                      \
    {                                                                          \
        if (l < HDIM) cw[px ^ 1][l] = xr[0];         /* stage x_{T+1} */       \
        int tf_ = (T) + 1 + PF; if (tf_ > NT - 1) tf_ = NT - 1;                \
        const float xf_ = xptr[(size_t)tf_ * tsx];                             \
        /* own row: 10 broadcast b128 reads, 20 pk_fma (2 chains) */           \
        f2 aA = f2{b1c, 0.f}, aB = f2{0.f, 0.f};                               \
        _Pragma("unroll")                                                      \
        for (int ii = 0; ii < 10; ++ii) {                                      \
            const f4 X = ((const f4*)&cw[px][0])[ii];                          \
            pk_fma(aA, f2{X.x, X.y}, w_own[2 * ii]);                           \
            pk_fma(aB, f2{X.z, X.w}, w_own[2 * ii + 1]);                       \
        }                                                                      \
        /* quarter operands (4 distinct addrs/wave, conflict-free) */          \
        const f4 Q0 = *(const f4*)&cw[px][qb];                                 \
        const f4 Q1 = *(const f4*)&cw[px][qb + 4];                             \
        const f4 Q2 = *(const f4*)&cw[px][qb + 8];                             \
        f2 sS = f2{0.f, 0.f}, sO = f2{0.f, 0.f};                               \
        pk_fma(sS, f2{Q0.x, Q0.y}, w_sh[0]); pk_fma(sO, f2{Q0.x, Q0.y}, w_oq[0]); \
        pk_fma(sS, f2{Q0.z, Q0.w}, w_sh[1]); pk_fma(sO, f2{Q0.z, Q0.w}, w_oq[1]); \
        pk_fma(sS, f2{Q1.x, Q1.y}, w_sh[2]); pk_fma(sO, f2{Q1.x, Q1.y}, w_oq[2]); \
        pk_fma(sS, f2{Q1.z, Q1.w}, w_sh[3]); pk_fma(sO, f2{Q1.z, Q1.w}, w_oq[3]); \
        pk_fma(sS, f2{Q2.x, Q2.y}, w_sh[4]); pk_fma(sO, f2{Q2.x, Q2.y}, w_oq[4]); \
        pk_fma(sS, f2{Q2.z, Q2.w}, w_sh[5]); pk_fma(sO, f2{Q2.z, Q2.w}, w_oq[5]); \
        const float vs = quad_sum(sS.x + sS.y);      /* shared o-row preact */ \
        const float vo = quad_sum(sO.x + sO.y);      /* out_{T-1} - bout   */  \
        /* own activation -> gwl[unit][gate] */                                \
        const float a1 = aA.x + aA.y + aB.x + aB.y;                            \
        const float e1 = EXP2(m1 * a1);                                        \
        gwl[u1][g1] = fmaf(B1, frcp(1.f + e1), A1);                            \
        /* shared o activation (quad writer) */                                \
        if (qi == 0) gwl[4 + qd][3] = frcp(1.f + EXP2(-L2E * (vs + bsc)));     \
        if (DO_STORE) { if (l == 0) *op = vo + bout; op += NGRID; }            \
        /* state update on unit owners; h_T -> next buffer */                  \
        asm volatile("s_waitcnt lgkmcnt(0)" ::: "memory");                     \
        if (l < HDIM) {                                                        \
            const f4 gv = *(const f4*)&gwl[l][0];    /* si, sf, tg, so */      \
            c = fmaf(gv.y, c, gv.x * gv.z);                                    \
            const float ec = EXP2(2.f * L2E * c);                              \
            cw[px ^ 1][20 + l] = gv.w * (1.f - 2.f * frcp(1.f + ec));          \
        }                                                                      \
        _Pragma("unroll")                                                      \
        for (int i_ = 0; i_ < PF - 1; ++i_) xr[i_] = xr[i_ + 1];               \
        xr[PF - 1] = xf_;                                                      \
        px ^= 1;                                                               \
    }

    // peeled first step (unabsorbed bias for chunk 0), then warm, then main.
    // unroll 2: px parity is compile-time (warm=64, main=256, both even).
    STEP(t0, false);
    b1c = b1f; bsc = bsf;
#pragma unroll 2
    for (int t = t0 + 1; t <= tstart; ++t) STEP(t, false);
#pragma unroll 2
    for (int t = tstart + 1; t <= tstart + CHUNK; ++t) STEP(t, true);
#undef STEP
}

extern "C" void kernel_launch(void* const* d_in, const int* in_sizes, int n_in,
                              void* d_out, int out_size, void* d_ws, size_t ws_size,
                              hipStream_t stream) {
    const float* x     = (const float*)d_in[0];
    const float* W_ih  = (const float*)d_in[1];
    const float* W_hh  = (const float*)d_in[2];
    const float* b_ih  = (const float*)d_in[3];
    const float* b_hh  = (const float*)d_in[4];
    const float* W_out = (const float*)d_in[5];
    const float* b_out = (const float*)d_in[6];
    float* out = (float*)d_out;

    lstm_w4_kernel<<<dim3(NCHUNK * NGRID / WPB), dim3(64 * WPB), 0, stream>>>(
        x, W_ih, W_hh, b_ih, b_hh, W_out, b_out, out);
}

// Round 13
// 401.184 us; speedup vs baseline: 1.0980x; 1.0070x over previous
//
#include <hip/hip_runtime.h>

#define NT     65536
#define NGRID  28
#define NX     19
#define HDIM   20
#define PF     4
#define CHUNK  256
#define WARM   64
#define NCHUNK (NT / CHUNK)   // 256
#define NTG    (NT * NGRID)   // 1,835,008
#define TGB    16             // (t,g) pairs per ax_kernel block

typedef float f2 __attribute__((ext_vector_type(2)));
typedef float f4 __attribute__((ext_vector_type(4)));

#if __has_builtin(__builtin_amdgcn_exp2f)
#define EXP2(x) __builtin_amdgcn_exp2f(x)
#else
#define EXP2(x) exp2f(x)
#endif
#define L2E 1.4426950408889634f

__device__ __forceinline__ float frcp(float v) { return __builtin_amdgcn_rcpf(v); }

__device__ __forceinline__ void pk_fma(f2& acc, f2 a, f2 b) {
    asm("v_pk_fma_f32 %0, %1, %2, %0" : "+v"(acc) : "v"(a), "v"(b));
}

// 4-lane (quad) sum via DPP quad_perm butterflies — all lanes get the sum.
__device__ __forceinline__ float quad_sum(float v) {
    float a = v + __builtin_bit_cast(float,
        __builtin_amdgcn_update_dpp(0, __builtin_bit_cast(int, v), 0xB1, 0xF, 0xF, true));
    return a + __builtin_bit_cast(float,
        __builtin_amdgcn_update_dpp(0, __builtin_bit_cast(int, a), 0x4E, 0xF, 0xF, true));
}

// h-part weight of gate row r, output-feedback absorbed:
// wh'[r][k] = W_hh[r][k] + W_ih[r][19]*W_out[k]   (k<20)
__device__ __forceinline__ float whp(const float* W_ih, const float* W_hh,
                                     const float* W_out, int r, int k) {
    if (k >= HDIM) return 0.f;
    return fmaf(W_ih[r * 20 + 19], W_out[k], W_hh[r * 20 + k]);
}

// ============================================================================
// Phase A: Ax[tg][r] = sum_{k<19} W_ih[r][k] * x[tg][k]  (no bias, no feedback
// col). Pure throughput GEMM over 1.8M independent (t,g). Thread = (tg_local,
// 4 consecutive rows); float4 writes perfectly coalesced.
// ============================================================================
__global__ __launch_bounds__(320) void ax_kernel(
    const float* __restrict__ x, const float* __restrict__ W_ih,
    float* __restrict__ Aws)
{
    __shared__ float xs[TGB * NX];     // 304
    __shared__ float ws[80 * NX];      // 1520
    const int    tid = threadIdx.x;
    const size_t tg0 = (size_t)blockIdx.x * TGB;

    if (tid < TGB * NX) xs[tid] = x[tg0 * NX + tid];
    for (int i = tid; i < 80 * NX; i += 320) {
        const int r = i / NX, k = i - NX * r;
        ws[i] = W_ih[r * 20 + k];
    }
    __syncthreads();

    const int tl = tid / 20;           // 0..15
    const int r4 = (tid % 20) * 4;     // 0,4,...,76
    const float* xp = &xs[tl * NX];
    float a0 = 0.f, a1 = 0.f, a2 = 0.f, a3 = 0.f;
#pragma unroll
    for (int k = 0; k < NX; ++k) {
        const float xv = xp[k];
        a0 = fmaf(xv, ws[(r4 + 0) * NX + k], a0);
        a1 = fmaf(xv, ws[(r4 + 1) * NX + k], a1);
        a2 = fmaf(xv, ws[(r4 + 2) * NX + k], a2);
        a3 = fmaf(xv, ws[(r4 + 3) * NX + k], a3);
    }
    *(f4*)&Aws[(tg0 + tl) * 80 + r4] = f4{a0, a1, a2, a3};
}

// ============================================================================
// Phase B: h-only recurrence. One wave per (chunk, cell). Lane l owns gate
// row l's h-dot (10 f2 weights); o-rows 64..79 quad-shared over 8-wide
// quarters of h (padded to 32) + DPP reduce; out row (w_out, h-only) quartered
// the same way. Ax streamed from workspace (2 dword loads/step, PF-deep
// pipeline). Per-lane weights 36 regs -> fits arch VGPRs, no AGPR copy tax
// (r5-r12: 80-reg weights parked in AGPRs cost ~130-190 cy/step in
// v_accvgpr_read copies; VOP3P cannot source AGPRs — r12 assembler reject).
// ============================================================================
__global__ __launch_bounds__(64, 2) void lstm_main_kernel(
    const float* __restrict__ Aws,    // (NT*NGRID, 80)
    const float* __restrict__ W_ih,   // (80, 20) — feedback col only
    const float* __restrict__ W_hh,   // (80, 20)
    const float* __restrict__ b_ih,   // (80,)
    const float* __restrict__ b_hh,   // (80,)
    const float* __restrict__ W_out,  // (1, 20)
    const float* __restrict__ b_out,  // (1,)
    float* __restrict__ out)          // (NT, NGRID)
{
    __shared__ __align__(16) float hb[2][32];    // h(20) | 0-pad(12), ping-pong
    __shared__ __align__(16) float gls[20][4];   // activated gates (si,sf,tg,so)

    const int b  = blockIdx.x;
    const int ci = b / NGRID;
    const int g  = b - ci * NGRID;
    const int l  = threadIdx.x;
    const int qd = l >> 2;          // quad 0..15
    const int qi = l & 3;           // lane-in-quad
    const int qb = 8 * qi;          // 8-wide quarter base in padded h

    const int tstart = ci * CHUNK;
    const int t0     = (ci == 0) ? 0 : tstart - WARM;

    const int g1 = l / HDIM;        // own row's gate class (0=i,1=f,2=g,3=o)
    const int u1 = l % HDIM;        // own row's unit

    const float bout = b_out[0];

    // own row l: 10 f2 over h[0..19]
    f2 whn[10];
#pragma unroll
    for (int j = 0; j < 10; ++j)
        whn[j] = f2{whp(W_ih, W_hh, W_out, l, 2 * j),
                    whp(W_ih, W_hh, W_out, l, 2 * j + 1)};
    const float bb1 = b_ih[l] + b_hh[l];
    const float bpf = fmaf(W_ih[l * 20 + 19], bout, bb1);
    float bpc = (ci == 0) ? bb1 : bpf;

    // quad-shared o-row rs = 64+qd: this lane's 8-wide quarter
    const int rs = 64 + qd;
    f2 wsq[4], woq[4];
#pragma unroll
    for (int m = 0; m < 4; ++m) {
        const int k0 = qb + 2 * m, k1 = k0 + 1;
        wsq[m] = f2{whp(W_ih, W_hh, W_out, rs, k0), whp(W_ih, W_hh, W_out, rs, k1)};
        woq[m] = f2{(k0 < HDIM) ? W_out[k0] : 0.f, (k1 < HDIM) ? W_out[k1] : 0.f};
    }
    const float bbs = b_ih[rs] + b_hh[rs];
    const float bsf = fmaf(W_ih[rs * 20 + 19], bout, bbs);
    float bsc = (ci == 0) ? bbs : bsf;

    // own-row activation (exp2 form): act = A1 + B1 * rcp(1 + exp2(m1*a))
    const float m1 = (g1 == 2) ? (2.f * L2E) : -L2E;
    const float A1 = (g1 == 2) ?  1.f :  0.f;
    const float B1 = (g1 == 2) ? -2.f :  1.f;

    // Ax streams: own row l and shared row 64+qd; stride NGRID*80 per t
    const float* axb = Aws + (size_t)g * 80 + l;
    const float* axs = Aws + (size_t)g * 80 + 64 + qd;
    const size_t tsa = (size_t)NGRID * 80;
    float ap[PF], as[PF];
#pragma unroll
    for (int p = 0; p < PF; ++p) {
        int tp = t0 + p; if (tp > NT - 1) tp = NT - 1;
        ap[p] = axb[(size_t)tp * tsa];
        as[p] = axs[(size_t)tp * tsa];
    }

    // prime LDS: h = 0, pads = 0 in both buffers
    if (l < 32) { hb[0][l] = 0.f; hb[1][l] = 0.f; }

    float  c  = 0.f;
    int    px = 0;
    float* op = out + (size_t)tstart * NGRID + g;

#define STEP(T, DO_STORE)                                                      \
    {                                                                          \
        int tf_ = (T) + PF; if (tf_ > NT - 1) tf_ = NT - 1;                    \
        const float fp_ = axb[(size_t)tf_ * tsa];                              \
        const float fs_ = axs[(size_t)tf_ * tsa];                              \
        /* own row: 5 broadcast b128 reads, 10 pk_fma; bias+Ax ride in acc */  \
        f2 aA = f2{ap[0], bpc}, aB = f2{0.f, 0.f};                             \
        _Pragma("unroll")                                                      \
        for (int ii = 0; ii < 5; ++ii) {                                       \
            const f4 X = ((const f4*)&hb[px][0])[ii];                          \
            pk_fma(aA, f2{X.x, X.y}, whn[2 * ii]);                             \
            pk_fma(aB, f2{X.z, X.w}, whn[2 * ii + 1]);                         \
        }                                                                      \
        /* quad quarters: 2 b128, 4 distinct addrs/wave */                     \
        const f4 Q0 = *(const f4*)&hb[px][qb];                                 \
        const f4 Q1 = *(const f4*)&hb[px][qb + 4];                             \
        f2 sS = f2{0.f, 0.f}, sO = f2{0.f, 0.f};                               \
        pk_fma(sS, f2{Q0.x, Q0.y}, wsq[0]); pk_fma(sO, f2{Q0.x, Q0.y}, woq[0]); \
        pk_fma(sS, f2{Q0.z, Q0.w}, wsq[1]); pk_fma(sO, f2{Q0.z, Q0.w}, woq[1]); \
        pk_fma(sS, f2{Q1.x, Q1.y}, wsq[2]); pk_fma(sO, f2{Q1.x, Q1.y}, woq[2]); \
        pk_fma(sS, f2{Q1.z, Q1.w}, wsq[3]); pk_fma(sO, f2{Q1.z, Q1.w}, woq[3]); \
        const float vs = quad_sum(sS.x + sS.y);                                \
        const float vo = quad_sum(sO.x + sO.y);     /* out_{T-1} - bout */     \
        const float a1 = aA.x + aA.y + aB.x + aB.y;                            \
        const float e1 = EXP2(m1 * a1);                                        \
        gls[u1][g1] = fmaf(B1, frcp(1.f + e1), A1);                            \
        if (qi == 0) gls[4 + qd][3] = frcp(1.f + EXP2(-L2E * (vs + as[0] + bsc))); \
        if (DO_STORE) { if (l == 0) *op = vo + bout; op += NGRID; }            \
        asm volatile("s_waitcnt lgkmcnt(0)" ::: "memory");                     \
        if (l < HDIM) {                              /* state update */        \
            const f4 gv = *(const f4*)&gls[l][0];    /* si, sf, tg, so */      \
            c = fmaf(gv.y, c, gv.x * gv.z);                                    \
            const float ec = EXP2(2.f * L2E * c);                              \
            hb[px ^ 1][l] = gv.w * (1.f - 2.f * frcp(1.f + ec));               \
        }                                                                      \
        _Pragma("unroll")                                                      \
        for (int i_ = 0; i_ < PF - 1; ++i_) { ap[i_] = ap[i_ + 1]; as[i_] = as[i_ + 1]; } \
        ap[PF - 1] = fp_; as[PF - 1] = fs_;                                    \
        px ^= 1;                                                               \
    }

    STEP(t0, false);                   // peeled (unabsorbed bias for chunk 0)
    bpc = bpf; bsc = bsf;
#pragma unroll 2
    for (int t = t0 + 1; t <= tstart; ++t) STEP(t, false);
#pragma unroll 2
    for (int t = tstart + 1; t <= tstart + CHUNK; ++t) STEP(t, true);
#undef STEP
}

// ============================================================================
// Fallback (r9 kernel verbatim): used when ws_size can't hold Ax.
// ============================================================================
__device__ __forceinline__ float gw_fb(const float* W_ih, const float* W_hh,
                                       const float* W_out, int r, int k) {
    if (k < NX) return W_ih[r * 20 + k];
    if (k >= 20 && k < 40)
        return fmaf(W_ih[r * 20 + 19], W_out[k - 20], W_hh[r * 20 + (k - 20)]);
    return 0.f;
}

__global__ __launch_bounds__(64, 2) void lstm_quad_kernel(
    const float* __restrict__ x, const float* __restrict__ W_ih,
    const float* __restrict__ W_hh, const float* __restrict__ b_ih,
    const float* __restrict__ b_hh, const float* __restrict__ W_out,
    const float* __restrict__ b_out, float* __restrict__ out)
{
    __shared__ __align__(16) float cls[2][48];
    __shared__ __align__(16) float gls[20][4];

    const int b  = blockIdx.x;
    const int ci = b / NGRID;
    const int g  = b - ci * NGRID;
    const int l  = threadIdx.x;
    const int qd = l >> 2;
    const int qi = l & 3;
    const int qb = 12 * qi;

    const int tstart = ci * CHUNK;
    const int t0     = (ci == 0) ? 0 : tstart - WARM;

    const int g1 = l / HDIM;
    const int u1 = l % HDIM;
    const float bout = b_out[0];

    f2 w_own[20];
#pragma unroll
    for (int kk = 0; kk < 20; ++kk)
        w_own[kk] = f2{gw_fb(W_ih, W_hh, W_out, l, 2 * kk),
                       gw_fb(W_ih, W_hh, W_out, l, 2 * kk + 1)};
    const float bb1 = b_ih[l] + b_hh[l];
    const float b1f = fmaf(W_ih[l * 20 + 19], bout, bb1);
    float b1c = (ci == 0) ? bb1 : b1f;

    const int rs = 64 + qd;
    f2 w_sh[6];
#pragma unroll
    for (int m = 0; m < 6; ++m)
        w_sh[m] = f2{gw_fb(W_ih, W_hh, W_out, rs, qb + 2 * m),
                     gw_fb(W_ih, W_hh, W_out, rs, qb + 2 * m + 1)};
    const float bbs = b_ih[rs] + b_hh[rs];
    const float bsf = fmaf(W_ih[rs * 20 + 19], bout, bbs);
    float bsc = (ci == 0) ? bbs : bsf;

    f2 w_oq[6];
#pragma unroll
    for (int m = 0; m < 6; ++m) {
        const int k0 = qb + 2 * m, k1 = k0 + 1;
        w_oq[m] = f2{(k0 >= 20 && k0 < 40) ? W_out[k0 - 20] : 0.f,
                     (k1 >= 20 && k1 < 40) ? W_out[k1 - 20] : 0.f};
    }

    const float m1 = (g1 == 2) ? (2.f * L2E) : -L2E;
    const float A1 = (g1 == 2) ?  1.f :  0.f;
    const float B1 = (g1 == 2) ? -2.f :  1.f;

    const int    kl   = (l < NX) ? l : 0;
    const float* xptr = x + (size_t)g * NX + kl;
    const size_t tsx  = (size_t)NGRID * NX;
    float xr[PF];
#pragma unroll
    for (int p = 0; p < PF; ++p) {
        int tp = t0 + 1 + p; if (tp > NT - 1) tp = NT - 1;
        xr[p] = xptr[(size_t)tp * tsx];
    }
    if (l < 8)    { cls[0][40 + l] = 0.f; cls[1][40 + l] = 0.f; }
    if (l < HDIM) { cls[0][20 + l] = 0.f; cls[0][l] = xptr[(size_t)t0 * tsx]; }

    float  c  = 0.f;
    int    px = 0;
    float* op = out + (size_t)tstart * NGRID + g;

#define STEPF(T, DO_STORE)                                                     \
    {                                                                          \
        if (l < HDIM) cls[px ^ 1][l] = xr[0];                                  \
        int tf_ = (T) + 1 + PF; if (tf_ > NT - 1) tf_ = NT - 1;                \
        const float xf_ = xptr[(size_t)tf_ * tsx];                             \
        f2 aA = f2{b1c, 0.f}, aB = f2{0.f, 0.f};                               \
        _Pragma("unroll")                                                      \
        for (int ii = 0; ii < 10; ++ii) {                                      \
            const f4 X = ((const f4*)&cls[px][0])[ii];                         \
            pk_fma(aA, f2{X.x, X.y}, w_own[2 * ii]);                           \
            pk_fma(aB, f2{X.z, X.w}, w_own[2 * ii + 1]);                       \
        }                                                                      \
        const f4 Q0 = *(const f4*)&cls[px][qb];                                \
        const f4 Q1 = *(const f4*)&cls[px][qb + 4];                            \
        const f4 Q2 = *(const f4*)&cls[px][qb + 8];                            \
        f2 sS = f2{0.f, 0.f}, sO = f2{0.f, 0.f};                               \
        pk_fma(sS, f2{Q0.x, Q0.y}, w_sh[0]); pk_fma(sO, f2{Q0.x, Q0.y}, w_oq[0]); \
        pk_fma(sS, f2{Q0.z, Q0.w}, w_sh[1]); pk_fma(sO, f2{Q0.z, Q0.w}, w_oq[1]); \
        pk_fma(sS, f2{Q1.x, Q1.y}, w_sh[2]); pk_fma(sO, f2{Q1.x, Q1.y}, w_oq[2]); \
        pk_fma(sS, f2{Q1.z, Q1.w}, w_sh[3]); pk_fma(sO, f2{Q1.z, Q1.w}, w_oq[3]); \
        pk_fma(sS, f2{Q2.x, Q2.y}, w_sh[4]); pk_fma(sO, f2{Q2.x, Q2.y}, w_oq[4]); \
        pk_fma(sS, f2{Q2.z, Q2.w}, w_sh[5]); pk_fma(sO, f2{Q2.z, Q2.w}, w_oq[5]); \
        const float vs = quad_sum(sS.x + sS.y);                                \
        const float vo = quad_sum(sO.x + sO.y);                                \
        const float a1 = aA.x + aA.y + aB.x + aB.y;                            \
        const float e1 = EXP2(m1 * a1);                                        \
        gls[u1][g1] = fmaf(B1, frcp(1.f + e1), A1);                            \
        if (qi == 0) gls[4 + qd][3] = frcp(1.f + EXP2(-L2E * (vs + bsc)));     \
        if (DO_STORE) { if (l == 0) *op = vo + bout; op += NGRID; }            \
        asm volatile("s_waitcnt lgkmcnt(0)" ::: "memory");                     \
        if (l < HDIM) {                                                        \
            const f4 gv = *(const f4*)&gls[l][0];                              \
            c = fmaf(gv.y, c, gv.x * gv.z);                                    \
            const float ec = EXP2(2.f * L2E * c);                              \
            cls[px ^ 1][20 + l] = gv.w * (1.f - 2.f * frcp(1.f + ec));         \
        }                                                                      \
        _Pragma("unroll")                                                      \
        for (int i_ = 0; i_ < PF - 1; ++i_) xr[i_] = xr[i_ + 1];               \
        xr[PF - 1] = xf_;                                                      \
        px ^= 1;                                                               \
    }

    STEPF(t0, false);
    b1c = b1f; bsc = bsf;
#pragma unroll 2
    for (int t = t0 + 1; t <= tstart; ++t) STEPF(t, false);
#pragma unroll 2
    for (int t = tstart + 1; t <= tstart + CHUNK; ++t) STEPF(t, true);
#undef STEPF
}

extern "C" void kernel_launch(void* const* d_in, const int* in_sizes, int n_in,
                              void* d_out, int out_size, void* d_ws, size_t ws_size,
                              hipStream_t stream) {
    const float* x     = (const float*)d_in[0];
    const float* W_ih  = (const float*)d_in[1];
    const float* W_hh  = (const float*)d_in[2];
    const float* b_ih  = (const float*)d_in[3];
    const float* b_hh  = (const float*)d_in[4];
    const float* W_out = (const float*)d_in[5];
    const float* b_out = (const float*)d_in[6];
    float* out = (float*)d_out;

    const size_t need = (size_t)NTG * 80 * sizeof(float);   // 587 MB
    if (ws_size >= need) {
        float* Aws = (float*)d_ws;
        ax_kernel<<<dim3(NTG / TGB), dim3(320), 0, stream>>>(x, W_ih, Aws);
        lstm_main_kernel<<<dim3(NCHUNK * NGRID), dim3(64), 0, stream>>>(
            Aws, W_ih, W_hh, b_ih, b_hh, W_out, b_out, out);
    } else {
        lstm_quad_kernel<<<dim3(NCHUNK * NGRID), dim3(64), 0, stream>>>(
            x, W_ih, W_hh, b_ih, b_hh, W_out, b_out, out);
    }
}